// Round 5
// baseline (156.553 us; speedup 1.0000x reference)
//
#include <hip/hip_runtime.h>

// Problem constants (fixed by the reference)
#define NXY   16
#define NZ    8
#define NS    2048      // states = 16*16*8
#define NT    2048      // tokens
#define NB    16        // stories
#define NL    16        // story length
#define NSENT 16        // tokens per sentence
#define NEGV  (-1e9f)

#define NBLK  512       // persistent grid: 2 blocks/CU, all co-resident
#define TT    16
#define LPAD  17        // odd pad -> conflict-free LDS stride

// LDS: smooth tile buffer and forward ping-pong buffers share storage.
struct __align__(16) ShMem {
    union {
        float A[256 * LPAD];   // 17408 B (smooth phase)
        float bufs[2][NS];     // 16384 B (forward phase)
    };
};

// Device-scope grid barrier: counter zeroed by a captured hipMemsetAsync
// before every launch (replay-safe, no leftover state). Release fence ->
// atomicAdd -> relaxed agent-scope spin -> acquire fence.
__device__ __forceinline__ void gbar(unsigned* ctr) {
    __syncthreads();
    if (threadIdx.x == 0) {
        __threadfence();                       // release: make writes visible
        atomicAdd(ctr, 1u);                    // device scope
        while (__hip_atomic_load(ctr, __ATOMIC_RELAXED, __HIP_MEMORY_SCOPE_AGENT)
               < (unsigned)NBLK) {
            __builtin_amdgcn_s_sleep(8);
        }
        __threadfence();                       // acquire: invalidate stale caches
    }
    __syncthreads();
}

__global__ __launch_bounds__(256, 2) void k_fused(
        const int* __restrict__ stories, const float* __restrict__ priors,
        const float* __restrict__ trans, const float* __restrict__ em,
        float* __restrict__ emT, float* __restrict__ eall,
        unsigned* __restrict__ ctrs, float* __restrict__ out) {
    __shared__ ShMem sh;
    const int tid = threadIdx.x;
    const int blk = blockIdx.x;

    // ---- Hoisted forward-phase inputs (blocks 0..15 only): issue the
    // scattered transition-row loads + priors NOW so their HBM/L3 latency
    // hides under the smooth phase. ~120 VGPRs held; budget is 256.
    float wr[8][7], pri[8];
    int   ixr[8][7];
    if (blk < NB) {
#pragma unroll
        for (int p = 0; p < 8; ++p) {
            const int h = tid + p * 256;
            const int x = h & 15, y = (h >> 4) & 15, z = h >> 8;
            const float* row = trans + (size_t)h * NS;
            wr[p][0] = row[h];                          ixr[p][0] = h;
            wr[p][1] = (x < 15) ? row[h + 1]   : NEGV;  ixr[p][1] = (x < 15) ? h + 1   : h;
            wr[p][2] = (x > 0)  ? row[h - 1]   : NEGV;  ixr[p][2] = (x > 0)  ? h - 1   : h;
            wr[p][3] = (y < 15) ? row[h + 16]  : NEGV;  ixr[p][3] = (y < 15) ? h + 16  : h;
            wr[p][4] = (y > 0)  ? row[h - 16]  : NEGV;  ixr[p][4] = (y > 0)  ? h - 16  : h;
            wr[p][5] = (z < 7)  ? row[h + 256] : NEGV;  ixr[p][5] = (z < 7)  ? h + 256 : h;
            wr[p][6] = (z < 6)  ? row[h + 512] : NEGV;  ixr[p][6] = (z < 6)  ? h + 512 : h;
            pri[p] = priors[h];
        }
    }

    // ---- Phase 1: smoothing (identity: log-mean-x then y == log(boxsum_y(
    // boxsum_x(exp(em)))) - log 25). 1024 (z, 16-token) tiles, 2 per block.
    const float LOG25 = 3.2188758248682006f;
#pragma unroll
    for (int it = 0; it < 2; ++it) {
        const int tile = blk * 2 + it;
        const int t0 = (tile & 127) * TT;
        const int z = tile >> 7;
        if (it) __syncthreads();           // A reuse across tiles

        const float* base = em + (size_t)z * 256 * NT + t0;
#pragma unroll
        for (int i = 0; i < 4; ++i) {
            int f = (i * 256 + tid) * 4;
            int xy = f >> 4, c = f & 15;
            float4 v = *(const float4*)(base + (size_t)xy * NT + c);
            float* dst = &sh.A[xy * LPAD + c];
            dst[0] = __expf(v.x); dst[1] = __expf(v.y);
            dst[2] = __expf(v.z); dst[3] = __expf(v.w);
        }
        __syncthreads();

        const int x = tid & 15, y = tid >> 4;
        int r[5];
#pragma unroll
        for (int k = 0; k < 5; ++k) {
            int xx = x + k - 2; xx = xx < 0 ? 0 : (xx > 15 ? 15 : xx);
            r[k] = (y * 16 + xx) * LPAD;
        }
        float rx[TT];
#pragma unroll
        for (int tt = 0; tt < TT; ++tt)
            rx[tt] = sh.A[r[0] + tt] + sh.A[r[1] + tt] + sh.A[r[2] + tt] +
                     sh.A[r[3] + tt] + sh.A[r[4] + tt];
        __syncthreads();
#pragma unroll
        for (int tt = 0; tt < TT; ++tt) sh.A[tid * LPAD + tt] = rx[tt];
        __syncthreads();
#pragma unroll
        for (int k = 0; k < 5; ++k) {
            int yy = y + k - 2; yy = yy < 0 ? 0 : (yy > 15 ? 15 : yy);
            r[k] = (yy * 16 + x) * LPAD;
        }
        float* ob = emT + (size_t)t0 * NS + z * 256 + tid;
#pragma unroll
        for (int tt = 0; tt < TT; ++tt) {
            float s = sh.A[r[0] + tt] + sh.A[r[1] + tt] + sh.A[r[2] + tt] +
                      sh.A[r[3] + tt] + sh.A[r[4] + tt];
            ob[(size_t)tt * NS] = __logf(s) - LOG25;
        }
    }

    gbar(&ctrs[0]);

    // ---- Phase 2: eall[b,l,s] = sum_j emT[tok[b,l,j], s]; 512 parallel
    // items = (sentence, half-of-states); fully coalesced float4 reads.
    {
        const int bl = blk >> 1, half = blk & 1;
        const int col = half * 256 + tid;                 // float4 index
        const float4* emT4 = (const float4*)emT;
        float4 a = make_float4(0.f, 0.f, 0.f, 0.f);
#pragma unroll 4
        for (int j = 0; j < NSENT; ++j) {
            int tok = stories[bl * NSENT + j];
            float4 v = emT4[(size_t)tok * (NS / 4) + col];
            a.x += v.x; a.y += v.y; a.z += v.z; a.w += v.w;
        }
        ((float4*)eall)[(size_t)bl * (NS / 4) + col] = a;
    }

    gbar(&ctrs[1]);

    if (blk >= NB) return;

    // ---- Phase 3: forward recursion, block = story, 8 states/thread,
    // weights/indices/priors already in registers.
    const int b = blk;
#pragma unroll
    for (int p = 0; p < 8; ++p) {
        const int h = tid + p * 256;
        float v = eall[(size_t)b * NL * NS + h] + pri[p];
        sh.bufs[0][h] = v;
        out[(size_t)b * NS + h] = v;                     // out[0][b][h]
    }
    __syncthreads();

    int cur = 1;
    for (int l = 1; l < NL; ++l) {
        const float* e = eall + ((size_t)b * NL + l) * NS;
        const float* pv = sh.bufs[cur ^ 1];
        float* cv = sh.bufs[cur];
#pragma unroll
        for (int p = 0; p < 8; ++p) {
            const int h = tid + p * 256;
            float v0 = wr[p][0] + pv[ixr[p][0]];
            float v1 = wr[p][1] + pv[ixr[p][1]];
            float v2 = wr[p][2] + pv[ixr[p][2]];
            float v3 = wr[p][3] + pv[ixr[p][3]];
            float v4 = wr[p][4] + pv[ixr[p][4]];
            float v5 = wr[p][5] + pv[ixr[p][5]];
            float v6 = wr[p][6] + pv[ixr[p][6]];
            float m = fmaxf(fmaxf(fmaxf(v0, v1), fmaxf(v2, v3)),
                            fmaxf(fmaxf(v4, v5), v6));
            float s = __expf(v0 - m) + __expf(v1 - m) + __expf(v2 - m) + __expf(v3 - m) +
                      __expf(v4 - m) + __expf(v5 - m) + __expf(v6 - m);
            float v = e[h] + m + __logf(s);
            cv[h] = v;
            out[((size_t)l * NB + b) * NS + h] = v;
        }
        __syncthreads();
        cur ^= 1;
    }
}

// ---------------------------------------------------------------------------
extern "C" void kernel_launch(void* const* d_in, const int* in_sizes, int n_in,
                              void* d_out, int out_size, void* d_ws, size_t ws_size,
                              hipStream_t stream) {
    (void)in_sizes; (void)n_in; (void)out_size; (void)ws_size;
    const int* stories  = (const int*)d_in[0];
    // d_in[1] = story_length (== NL), unused
    const float* priors = (const float*)d_in[2];
    const float* trans  = (const float*)d_in[3];
    const float* em     = (const float*)d_in[4];
    float* out = (float*)d_out;

    float* emT  = (float*)d_ws;                              // [NT][NS]    16 MB
    float* eall = emT + (size_t)NT * NS;                     // [NB*NL][NS]  2 MB
    unsigned* ctrs = (unsigned*)((char*)d_ws + (32u << 20)); // isolated line

    hipMemsetAsync(ctrs, 0, 2 * sizeof(unsigned), stream);   // capture-safe
    k_fused<<<dim3(NBLK), 256, 0, stream>>>(stories, priors, trans, em,
                                            emT, eall, ctrs, out);
}

// Round 6
// 47.758 us; speedup vs baseline: 3.2780x; 3.2780x over previous
//
#include <hip/hip_runtime.h>

// Problem constants (fixed by the reference)
#define NXY   16
#define NZ    8
#define NS    2048      // states = 16*16*8
#define NT    2048      // tokens
#define NB    16        // stories
#define NL    16        // story length
#define NSENT 16        // tokens per sentence
#define NEGV  (-1e9f)

// ---------------------------------------------------------------------------
// K1 v2: fused smoothing + transpose, register x-pass.
// Identity: windowed log-mean along x then y ==
//   log( boxsum_y( boxsum_x( exp(em) ) ) ) - log 25
//
// Thread (y, toff) owns the full 16-element x-line in registers:
//   - 16 coalesced (64B/16-lane-group) strided loads, exp in regs
//   - clamped 5-wide x-box-sum in regs  (no LDS, no barrier)
//   - one LDS write per x  ->  S[s_local][toff], stride 17 (17 coprime 32
//     -> conflict-free both on write (lanes vary toff,y) and read (lanes
//     vary s))
//   - ONE barrier
//   - thread s = tid: y-box-sum = 5 LDS reads per token, log, coalesced
//     256B transposed stores to emT[t][s]
// vs round-2: LDS ops ~190 -> ~96 per thread, barriers 3 -> 1.
// ---------------------------------------------------------------------------
#define TT   16
#define SPAD 17

__global__ __launch_bounds__(256) void k_smooth(const float* __restrict__ em,
                                                float* __restrict__ emT) {
    __shared__ float S[256 * SPAD];   // 17408 B
    const int tid = threadIdx.x;
    const int t0 = blockIdx.x * TT;
    const int z = blockIdx.y;
    const int toff = tid & 15, y = tid >> 4;

    // load the x-line, exp in registers
    const float* base = em + ((size_t)z * 256 + y * 16) * NT + t0 + toff;
    float ex[16];
#pragma unroll
    for (int x = 0; x < 16; ++x)
        ex[x] = __expf(base[(size_t)x * NT]);

    // clamped 5-wide x-box-sum in registers, store once to LDS
#pragma unroll
    for (int x = 0; x < 16; ++x) {
        const int xm2 = x - 2 < 0 ? 0 : x - 2, xm1 = x - 1 < 0 ? 0 : x - 1;
        const int xp1 = x + 1 > 15 ? 15 : x + 1, xp2 = x + 2 > 15 ? 15 : x + 2;
        S[(y * 16 + x) * SPAD + toff] = ex[xm2] + ex[xm1] + ex[x] + ex[xp1] + ex[xp2];
    }
    __syncthreads();

    // y-box-sum + log + transposed write; thread owns state s = tid
    const int x2 = tid & 15, y2 = tid >> 4;
    int ry[5];
#pragma unroll
    for (int k = 0; k < 5; ++k) {
        int yy = y2 + k - 2; yy = yy < 0 ? 0 : (yy > 15 ? 15 : yy);
        ry[k] = (yy * 16 + x2) * SPAD;
    }
    const float LOG25 = 3.2188758248682006f;   // log(5)+log(5)
    float* ob = emT + (size_t)t0 * NS + z * 256 + tid;
#pragma unroll
    for (int t = 0; t < TT; ++t) {
        float a = S[ry[0] + t] + S[ry[1] + t] + S[ry[2] + t] + S[ry[3] + t] + S[ry[4] + t];
        ob[(size_t)t * NS] = __logf(a) - LOG25;
    }
}

// ---------------------------------------------------------------------------
// K2: e_all[b,l,s] = sum_j em_T[tok[b,l,j], s]   (contiguous row reads)
// (round-2 proven version, unchanged)
// ---------------------------------------------------------------------------
__global__ __launch_bounds__(256) void k_eall(const int* __restrict__ stories,
                                              const float* __restrict__ emT,
                                              float* __restrict__ eall) {
    const int bl = blockIdx.x;
    const int col = blockIdx.y * 256 + threadIdx.x;
    __shared__ int toks[NSENT];
    if (threadIdx.x < NSENT) toks[threadIdx.x] = stories[bl * NSENT + threadIdx.x];
    __syncthreads();

    float4 a = make_float4(0.f, 0.f, 0.f, 0.f);
#pragma unroll 4
    for (int j = 0; j < NSENT; ++j) {
        float4 v = ((const float4*)(emT + (size_t)toks[j] * NS))[col];
        a.x += v.x; a.y += v.y; a.z += v.z; a.w += v.w;
    }
    ((float4*)(eall + (size_t)bl * NS))[col] = a;
}

// ---------------------------------------------------------------------------
// K3: forward recursion (round-2 proven version, unchanged): one block per
// story, 1024 threads x 2 states, weights + clamped indices in registers,
// prev/cur ping-pong in LDS.
// ---------------------------------------------------------------------------
__global__ __launch_bounds__(1024) void k_forward(const float* __restrict__ trans,
                                                  const float* __restrict__ priors,
                                                  const float* __restrict__ eall,
                                                  float* __restrict__ out) {
    __shared__ float buf0[NS];
    __shared__ float buf1[NS];
    const int b = blockIdx.x;
    const int tid = threadIdx.x;

    float wr[2][7];
    int   ix[2][7];
#pragma unroll
    for (int p = 0; p < 2; ++p) {
        const int h = tid + p * 1024;
        const int x = h & 15, y = (h >> 4) & 15, z = h >> 8;
        const float* row = trans + (size_t)h * NS;
        wr[p][0] = row[h];                          ix[p][0] = h;
        wr[p][1] = (x < 15) ? row[h + 1]   : NEGV;  ix[p][1] = (x < 15) ? h + 1   : h;
        wr[p][2] = (x > 0)  ? row[h - 1]   : NEGV;  ix[p][2] = (x > 0)  ? h - 1   : h;
        wr[p][3] = (y < 15) ? row[h + 16]  : NEGV;  ix[p][3] = (y < 15) ? h + 16  : h;
        wr[p][4] = (y > 0)  ? row[h - 16]  : NEGV;  ix[p][4] = (y > 0)  ? h - 16  : h;
        wr[p][5] = (z < 7)  ? row[h + 256] : NEGV;  ix[p][5] = (z < 7)  ? h + 256 : h;
        wr[p][6] = (z < 6)  ? row[h + 512] : NEGV;  ix[p][6] = (z < 6)  ? h + 512 : h;
        float v = eall[(size_t)b * NL * NS + h] + priors[h];
        buf0[h] = v;
        out[(size_t)b * NS + h] = v;
    }
    __syncthreads();

    float* prev = buf0;
    float* cur = buf1;
    for (int l = 1; l < NL; ++l) {
        const float* e = eall + ((size_t)b * NL + l) * NS;
#pragma unroll
        for (int p = 0; p < 2; ++p) {
            const int h = tid + p * 1024;
            float v0 = wr[p][0] + prev[ix[p][0]];
            float v1 = wr[p][1] + prev[ix[p][1]];
            float v2 = wr[p][2] + prev[ix[p][2]];
            float v3 = wr[p][3] + prev[ix[p][3]];
            float v4 = wr[p][4] + prev[ix[p][4]];
            float v5 = wr[p][5] + prev[ix[p][5]];
            float v6 = wr[p][6] + prev[ix[p][6]];
            float m = fmaxf(fmaxf(fmaxf(v0, v1), fmaxf(v2, v3)),
                            fmaxf(fmaxf(v4, v5), v6));
            float s = __expf(v0 - m) + __expf(v1 - m) + __expf(v2 - m) + __expf(v3 - m) +
                      __expf(v4 - m) + __expf(v5 - m) + __expf(v6 - m);
            float v = e[h] + m + __logf(s);
            cur[h] = v;
            out[((size_t)l * NB + b) * NS + h] = v;
        }
        __syncthreads();
        float* tmp = prev; prev = cur; cur = tmp;
    }
}

// ---------------------------------------------------------------------------
extern "C" void kernel_launch(void* const* d_in, const int* in_sizes, int n_in,
                              void* d_out, int out_size, void* d_ws, size_t ws_size,
                              hipStream_t stream) {
    (void)in_sizes; (void)n_in; (void)out_size; (void)ws_size;
    const int* stories  = (const int*)d_in[0];
    // d_in[1] = story_length (== NL), unused
    const float* priors = (const float*)d_in[2];
    const float* trans  = (const float*)d_in[3];
    const float* em     = (const float*)d_in[4];
    float* out = (float*)d_out;

    float* emT  = (float*)d_ws;                    // [NT][NS]   16 MB
    float* eall = emT + (size_t)NT * NS;           // [NB*NL][NS] 2 MB

    k_smooth<<<dim3(NT / TT, NZ), 256, 0, stream>>>(em, emT);
    k_eall<<<dim3(NB * NL, 2), 256, 0, stream>>>(stories, emT, eall);
    k_forward<<<dim3(NB), 1024, 0, stream>>>(trans, priors, eall, out);
}